// Round 7
// baseline (669.607 us; speedup 1.0000x reference)
//
#include <hip/hip_runtime.h>
#include <math.h>

#define NN 50000
#define NE 1600000
#define CH 128
#define LAT 32
#define NB 196  // ceil(NN/256)

__device__ __forceinline__ unsigned short f2bf(float f) {  // RNE round to bf16
  unsigned int u = __float_as_uint(f);
  unsigned int r = u + 0x7FFFu + ((u >> 16) & 1u);
  return (unsigned short)(r >> 16);
}
__device__ __forceinline__ float bf2f(unsigned short s) {
  return __uint_as_float(((unsigned int)s) << 16);
}
__device__ __forceinline__ float bflo(unsigned int u) {  // low bf16 of packed pair
  return __uint_as_float(u << 16);
}
__device__ __forceinline__ float bfhi(unsigned int u) {  // high bf16 of packed pair
  return __uint_as_float(u & 0xffff0000u);
}

// ---------------- fp32 -> bf16 table convert ----------------
__global__ void k_tobf16(const float* __restrict__ in, unsigned short* __restrict__ out,
                         int n4) {
  int i = blockIdx.x * 256 + threadIdx.x;
  if (i < n4) {
    float4 v = reinterpret_cast<const float4*>(in)[i];
    ushort4 o;
    o.x = f2bf(v.x); o.y = f2bf(v.y); o.z = f2bf(v.z); o.w = f2bf(v.w);
    reinterpret_cast<ushort4*>(out)[i] = o;
  }
}

// ---------------- CSR build ----------------
__global__ void k_hist(const int* __restrict__ dst, int* __restrict__ deg) {
  int e = blockIdx.x * 256 + threadIdx.x;
  if (e < NE) atomicAdd(&deg[dst[e]], 1);
}

__global__ void k_scan1(const int* __restrict__ deg, int* __restrict__ bsum) {
  __shared__ int red[256];
  int i = blockIdx.x * 256 + threadIdx.x;
  red[threadIdx.x] = (i < NN) ? deg[i] : 0;
  __syncthreads();
  for (int s = 128; s > 0; s >>= 1) {
    if (threadIdx.x < s) red[threadIdx.x] += red[threadIdx.x + s];
    __syncthreads();
  }
  if (threadIdx.x == 0) bsum[blockIdx.x] = red[0];
}

__global__ void k_scan2(const int* __restrict__ bsum, int* __restrict__ boff) {
  __shared__ int tmp[256];
  int t = threadIdx.x;
  int v = (t < NB) ? bsum[t] : 0;
  tmp[t] = v;
  __syncthreads();
  for (int off = 1; off < 256; off <<= 1) {
    int add = (t >= off) ? tmp[t - off] : 0;
    __syncthreads();
    tmp[t] += add;
    __syncthreads();
  }
  if (t < NB) boff[t] = tmp[t] - v;  // exclusive
}

__global__ void k_scan3(const int* __restrict__ deg, const int* __restrict__ boff,
                        int* __restrict__ row_start, int* __restrict__ cursor) {
  __shared__ int tmp[256];
  int t = threadIdx.x;
  int i = blockIdx.x * 256 + t;
  int v = (i < NN) ? deg[i] : 0;
  tmp[t] = v;
  __syncthreads();
  for (int off = 1; off < 256; off <<= 1) {
    int add = (t >= off) ? tmp[t - off] : 0;
    __syncthreads();
    tmp[t] += add;
    __syncthreads();
  }
  int excl = tmp[t] - v + boff[blockIdx.x];
  if (i < NN) { row_start[i] = excl; cursor[i] = excl; }
}

__global__ void k_fill(const int* __restrict__ src, const int* __restrict__ dst,
                       int* __restrict__ cursor, int* __restrict__ eid) {
  int e = blockIdx.x * 256 + threadIdx.x;
  if (e < NE) {
    int d = dst[e];
    int pos = atomicAdd(&cursor[d], 1);
    eid[pos] = src[e];
  }
}

// ---------------- fused SAGE layer: bf16 pull-aggregate + fp32 GEMM + ReLU ----
// 16 nodes/block (3125 blocks = 12.2/CU: fills the 8-block LDS/wave budget and
// shrinks tail imbalance). Phase 1: half-wave per node, serial edge loop with
// unroll-8 (8 row-gathers in flight), bit-exact summation order. fp32 row-major
// LDS tiles (16KB): float4 writes and 2-rows-per-wave reads are conflict-free.
// Phase 2: acc[2][4] per thread, weight rows broadcast via L1.
__global__ __launch_bounds__(256, 8) void k_sage2(
    const unsigned short* __restrict__ featb, const float* __restrict__ feat32,
    const int* __restrict__ deg, const int* __restrict__ row_start,
    const int* __restrict__ eid,
    const float* __restrict__ Wl, const float* __restrict__ Wr,
    const float* __restrict__ bias, unsigned short* __restrict__ outb) {
  __shared__ float mean_s[16][128];
  __shared__ float h_s[16][128];
  int tid = threadIdx.x;
  int nbase = blockIdx.x * 16;
  int hw = tid >> 5, q = tid & 31;
  int q4 = q * 4;

  // Phase 1: pull aggregation; half-wave hw handles nodes hw and hw+8
  for (int n = hw; n < 16; n += 8) {
    int v = nbase + n;
    float ax = 0.f, ay = 0.f, az = 0.f, aw = 0.f;
    float hx = 0.f, hy = 0.f, hz = 0.f, hwv = 0.f;
    if (v < NN) {
      int r0 = row_start[v];
      int dg = deg[v];
      int i = 0;
      for (; i + 7 < dg; i += 8) {
        int s[8];
#pragma unroll
        for (int u = 0; u < 8; ++u) s[u] = eid[r0 + i + u];
#pragma unroll
        for (int u = 0; u < 8; ++u) {
          ushort4 a = *reinterpret_cast<const ushort4*>(featb + (size_t)s[u] * CH + q4);
          ax += bf2f(a.x); ay += bf2f(a.y); az += bf2f(a.z); aw += bf2f(a.w);
        }
      }
      for (; i < dg; ++i) {
        int s0 = eid[r0 + i];
        ushort4 a = *reinterpret_cast<const ushort4*>(featb + (size_t)s0 * CH + q4);
        ax += bf2f(a.x); ay += bf2f(a.y); az += bf2f(a.z); aw += bf2f(a.w);
      }
      float r = 1.0f / (float)max(dg, 1);
      ax *= r; ay *= r; az *= r; aw *= r;
      if (feat32) {
        float4 hh = *reinterpret_cast<const float4*>(feat32 + (size_t)v * CH + q4);
        hx = hh.x; hy = hh.y; hz = hh.z; hwv = hh.w;
      } else {
        ushort4 hb = *reinterpret_cast<const ushort4*>(featb + (size_t)v * CH + q4);
        hx = bf2f(hb.x); hy = bf2f(hb.y); hz = bf2f(hb.z); hwv = bf2f(hb.w);
      }
    }
    *reinterpret_cast<float4*>(&mean_s[n][q4]) = make_float4(ax, ay, az, aw);
    *reinterpret_cast<float4*>(&h_s[n][q4]) = make_float4(hx, hy, hz, hwv);
  }
  __syncthreads();

  // Phase 2: out[16][128] = mean @ Wl + h @ Wr + b, ReLU (fp32 accum)
  int jg = tid & 31, ng = tid >> 5;
  int j0 = jg * 4, nl = ng * 2;
  float acc[2][4];
#pragma unroll
  for (int a = 0; a < 2; a++)
#pragma unroll
    for (int b = 0; b < 4; b++) acc[a][b] = 0.f;

#pragma unroll 4
  for (int k = 0; k < 128; ++k) {
    float4 wl = *reinterpret_cast<const float4*>(Wl + k * CH + j0);
    float4 wr = *reinterpret_cast<const float4*>(Wr + k * CH + j0);
#pragma unroll
    for (int n = 0; n < 2; ++n) {
      float m = mean_s[nl + n][k];
      float hv = h_s[nl + n][k];
      acc[n][0] += m * wl.x + hv * wr.x;
      acc[n][1] += m * wl.y + hv * wr.y;
      acc[n][2] += m * wl.z + hv * wr.z;
      acc[n][3] += m * wl.w + hv * wr.w;
    }
  }

  float4 bb = *reinterpret_cast<const float4*>(bias + j0);
#pragma unroll
  for (int n = 0; n < 2; ++n) {
    int v = nbase + nl + n;
    if (v < NN) {
      ushort4 ob;
      ob.x = f2bf(fmaxf(acc[n][0] + bb.x, 0.f));
      ob.y = f2bf(fmaxf(acc[n][1] + bb.y, 0.f));
      ob.z = f2bf(fmaxf(acc[n][2] + bb.z, 0.f));
      ob.w = f2bf(fmaxf(acc[n][3] + bb.w, 0.f));
      *reinterpret_cast<ushort4*>(outb + (size_t)v * CH + j0) = ob;
    }
  }
}

// ---------------- mu / logvar heads + reparameterize (bf16 h2 in, bf16 z out) --
__global__ __launch_bounds__(256) void k_heads(
    const unsigned short* __restrict__ h2b, const float* __restrict__ eps,
    const float* __restrict__ Wmu, const float* __restrict__ bmu,
    const float* __restrict__ Wlv, const float* __restrict__ blv,
    float* __restrict__ mu_out, float* __restrict__ lv_out,
    unsigned short* __restrict__ zb) {
  __shared__ float hs[32][132];  // +4 pad kills bank conflict on hs[n][k]
  int tid = threadIdx.x;
  int nbase = blockIdx.x * 32;

  for (int f = tid; f < 1024; f += 256) {
    int row = f >> 5;
    int c4 = (f & 31) * 4;
    int v = nbase + row;
    float4 hh = make_float4(0.f, 0.f, 0.f, 0.f);
    if (v < NN) {
      ushort4 hb = *reinterpret_cast<const ushort4*>(h2b + (size_t)v * CH + c4);
      hh = make_float4(bf2f(hb.x), bf2f(hb.y), bf2f(hb.z), bf2f(hb.w));
    }
    *reinterpret_cast<float4*>(&hs[row][c4]) = hh;
  }
  __syncthreads();

  int n = tid >> 3;
  int j0 = (tid & 7) * 4;
  float am[4] = {0.f, 0.f, 0.f, 0.f};
  float al[4] = {0.f, 0.f, 0.f, 0.f};
#pragma unroll 4
  for (int k = 0; k < 128; ++k) {
    float4 wm = *reinterpret_cast<const float4*>(Wmu + k * LAT + j0);
    float4 wv = *reinterpret_cast<const float4*>(Wlv + k * LAT + j0);
    float hv = hs[n][k];
    am[0] += hv * wm.x; am[1] += hv * wm.y; am[2] += hv * wm.z; am[3] += hv * wm.w;
    al[0] += hv * wv.x; al[1] += hv * wv.y; al[2] += hv * wv.z; al[3] += hv * wv.w;
  }
  int v = nbase + n;
  if (v < NN) {
    float4 bm = *reinterpret_cast<const float4*>(bmu + j0);
    float4 bl = *reinterpret_cast<const float4*>(blv + j0);
    float4 e4 = *reinterpret_cast<const float4*>(eps + (size_t)v * LAT + j0);
    float4 mu, lv;
    mu.x = am[0] + bm.x; mu.y = am[1] + bm.y; mu.z = am[2] + bm.z; mu.w = am[3] + bm.w;
    lv.x = al[0] + bl.x; lv.y = al[1] + bl.y; lv.z = al[2] + bl.z; lv.w = al[3] + bl.w;
    ushort4 zz;
    zz.x = f2bf(mu.x + e4.x * expf(0.5f * lv.x));
    zz.y = f2bf(mu.y + e4.y * expf(0.5f * lv.y));
    zz.z = f2bf(mu.z + e4.z * expf(0.5f * lv.z));
    zz.w = f2bf(mu.w + e4.w * expf(0.5f * lv.w));
    *reinterpret_cast<float4*>(mu_out + (size_t)v * LAT + j0) = mu;
    *reinterpret_cast<float4*>(lv_out + (size_t)v * LAT + j0) = lv;
    *reinterpret_cast<ushort4*>(zb + (size_t)v * LAT + j0) = zz;
  }
}

// ---------------- edge decode: sigmoid(z[src] . z[dst]), bf16 z ----------------
// 4 lanes/edge, 16B loads (8 bf16 channels per lane), 2-level shfl reduce.
__global__ void k_decode(const int* __restrict__ src, const int* __restrict__ dst,
                         const unsigned short* __restrict__ zb,
                         float* __restrict__ probs) {
  int t = blockIdx.x * 256 + threadIdx.x;
  int e = t >> 2, part = t & 3;
  if (e >= NE) return;
  int s = src[e], d = dst[e];
  uint4 ua = *reinterpret_cast<const uint4*>(zb + (size_t)s * LAT + part * 8);
  uint4 ub = *reinterpret_cast<const uint4*>(zb + (size_t)d * LAT + part * 8);
  float p = bflo(ua.x) * bflo(ub.x) + bfhi(ua.x) * bfhi(ub.x)
          + bflo(ua.y) * bflo(ub.y) + bfhi(ua.y) * bfhi(ub.y)
          + bflo(ua.z) * bflo(ub.z) + bfhi(ua.z) * bfhi(ub.z)
          + bflo(ua.w) * bflo(ub.w) + bfhi(ua.w) * bfhi(ub.w);
  p += __shfl_xor(p, 1);
  p += __shfl_xor(p, 2);
  if (part == 0) probs[e] = 1.0f / (1.0f + expf(-p));
}

extern "C" void kernel_launch(void* const* d_in, const int* in_sizes, int n_in,
                              void* d_out, int out_size, void* d_ws, size_t ws_size,
                              hipStream_t stream) {
  const float* x   = (const float*)d_in[0];
  const int*   ei  = (const int*)d_in[1];
  const float* eps = (const float*)d_in[2];
  const float* Wl0 = (const float*)d_in[3];
  const float* Wr0 = (const float*)d_in[4];
  const float* b0  = (const float*)d_in[5];
  const float* Wl1 = (const float*)d_in[6];
  const float* Wr1 = (const float*)d_in[7];
  const float* b1  = (const float*)d_in[8];
  const float* Wmu = (const float*)d_in[9];
  const float* bmu = (const float*)d_in[10];
  const float* Wlv = (const float*)d_in[11];
  const float* blv = (const float*)d_in[12];
  const int* src = ei;
  const int* dst = ei + NE;

  // workspace layout (~45.5 MiB)
  int* iws = (int*)d_ws;
  int* deg       = iws;                       // NN
  int* row_start = deg + NN;                  // NN
  int* cursor    = row_start + NN;            // NN
  int* bsum      = cursor + NN;               // 256
  int* boff      = bsum + 256;                // 256
  int* eid       = boff + 256;                // NE
  unsigned short* xb  = (unsigned short*)(eid + NE);  // NN*CH bf16
  unsigned short* h1b = xb + (size_t)NN * CH;         // NN*CH bf16
  unsigned short* h2b = h1b + (size_t)NN * CH;        // NN*CH bf16
  unsigned short* zb  = xb;  // xb dead after layer 0; NN*LAT bf16 fits

  float* probs  = (float*)d_out;              // NE
  float* mu_out = probs + NE;                 // NN*LAT
  float* lv_out = mu_out + NN * LAT;          // NN*LAT

  hipMemsetAsync(deg, 0, NN * sizeof(int), stream);

  k_tobf16<<<(NN * CH / 4 + 255) / 256, 256, 0, stream>>>(x, xb, NN * CH / 4);
  k_hist <<<(NE + 255) / 256, 256, 0, stream>>>(dst, deg);
  k_scan1<<<NB, 256, 0, stream>>>(deg, bsum);
  k_scan2<<<1, 256, 0, stream>>>(bsum, boff);
  k_scan3<<<NB, 256, 0, stream>>>(deg, boff, row_start, cursor);
  k_fill <<<(NE + 255) / 256, 256, 0, stream>>>(src, dst, cursor, eid);

  // layer 0: gather bf16(x), self exact fp32 x, emit bf16 h1
  k_sage2<<<(NN + 15) / 16, 256, 0, stream>>>(xb, x, deg, row_start, eid,
                                              Wl0, Wr0, b0, h1b);
  // layer 1: gather + self bf16 h1, emit bf16 h2
  k_sage2<<<(NN + 15) / 16, 256, 0, stream>>>(h1b, nullptr, deg, row_start, eid,
                                              Wl1, Wr1, b1, h2b);

  k_heads<<<(NN + 31) / 32, 256, 0, stream>>>(h2b, eps, Wmu, bmu, Wlv, blv,
                                              mu_out, lv_out, zb);
  k_decode<<<(NE * 4 + 255) / 256, 256, 0, stream>>>(src, dst, zb, probs);
}

// Round 9
// 643.708 us; speedup vs baseline: 1.0402x; 1.0402x over previous
//
#include <hip/hip_runtime.h>
#include <math.h>

#define NN 50000
#define NE 1600000
#define CH 128
#define LAT 32
#define NB 196  // ceil(NN/256)

__device__ __forceinline__ unsigned short f2bf(float f) {  // RNE round to bf16
  unsigned int u = __float_as_uint(f);
  unsigned int r = u + 0x7FFFu + ((u >> 16) & 1u);
  return (unsigned short)(r >> 16);
}
__device__ __forceinline__ float bf2f(unsigned short s) {
  return __uint_as_float(((unsigned int)s) << 16);
}
__device__ __forceinline__ float bflo(unsigned int u) {
  return __uint_as_float(u << 16);
}
__device__ __forceinline__ float bfhi(unsigned int u) {
  return __uint_as_float(u & 0xffff0000u);
}

// ---------------- fp32 -> bf16 table convert ----------------
__global__ void k_tobf16(const float* __restrict__ in, unsigned short* __restrict__ out,
                         int n4) {
  int i = blockIdx.x * 256 + threadIdx.x;
  if (i < n4) {
    float4 v = reinterpret_cast<const float4*>(in)[i];
    ushort4 o;
    o.x = f2bf(v.x); o.y = f2bf(v.y); o.z = f2bf(v.z); o.w = f2bf(v.w);
    reinterpret_cast<ushort4*>(out)[i] = o;
  }
}

// ---------------- CSR build (proven R5-R7 kernels, unchanged) ----------------
__global__ void k_hist(const int* __restrict__ dst, int* __restrict__ deg) {
  int e = blockIdx.x * 256 + threadIdx.x;
  if (e < NE) atomicAdd(&deg[dst[e]], 1);
}

__global__ void k_scan1(const int* __restrict__ deg, int* __restrict__ bsum) {
  __shared__ int red[256];
  int i = blockIdx.x * 256 + threadIdx.x;
  red[threadIdx.x] = (i < NN) ? deg[i] : 0;
  __syncthreads();
  for (int s = 128; s > 0; s >>= 1) {
    if (threadIdx.x < s) red[threadIdx.x] += red[threadIdx.x + s];
    __syncthreads();
  }
  if (threadIdx.x == 0) bsum[blockIdx.x] = red[0];
}

__global__ void k_scan2(const int* __restrict__ bsum, int* __restrict__ boff) {
  __shared__ int tmp[256];
  int t = threadIdx.x;
  int v = (t < NB) ? bsum[t] : 0;
  tmp[t] = v;
  __syncthreads();
  for (int off = 1; off < 256; off <<= 1) {
    int add = (t >= off) ? tmp[t - off] : 0;
    __syncthreads();
    tmp[t] += add;
    __syncthreads();
  }
  if (t < NB) boff[t] = tmp[t] - v;  // exclusive
}

__global__ void k_scan3(const int* __restrict__ deg, const int* __restrict__ boff,
                        int* __restrict__ row_start, int* __restrict__ cursor) {
  __shared__ int tmp[256];
  int t = threadIdx.x;
  int i = blockIdx.x * 256 + t;
  int v = (i < NN) ? deg[i] : 0;
  tmp[t] = v;
  __syncthreads();
  for (int off = 1; off < 256; off <<= 1) {
    int add = (t >= off) ? tmp[t - off] : 0;
    __syncthreads();
    tmp[t] += add;
    __syncthreads();
  }
  int excl = tmp[t] - v + boff[blockIdx.x];
  if (i < NN) { row_start[i] = excl; cursor[i] = excl; }
}

__global__ void k_fill(const int* __restrict__ src, const int* __restrict__ dst,
                       int* __restrict__ cursor, int* __restrict__ eid) {
  int e = blockIdx.x * 256 + threadIdx.x;
  if (e < NE) {
    int d = dst[e];
    int pos = atomicAdd(&cursor[d], 1);
    eid[pos] = src[e];
  }
}

// ---------------- fused SAGE layer (the ONE new kernel this round) ----------
// 32 nodes/block. Phase 1: half-wave per node, gather batched 8-deep
// (8 eids -> 8 row loads into regs -> accumulate); (256,4) -> VGPR cap 128.
// fp32 row-major LDS (32KB, zero conflicts measured R4). Phase 2: 4x4 acc.
__global__ __launch_bounds__(256, 4) void k_sage2(
    const unsigned short* __restrict__ featb, const float* __restrict__ feat32,
    const int* __restrict__ deg, const int* __restrict__ row_start,
    const int* __restrict__ eid,
    const float* __restrict__ Wl, const float* __restrict__ Wr,
    const float* __restrict__ bias,
    float* __restrict__ outf, unsigned short* __restrict__ outb) {
  __shared__ float mean_s[32][128];
  __shared__ float h_s[32][128];
  int tid = threadIdx.x;
  int nbase = blockIdx.x * 32;
  int hw = tid >> 5, q = tid & 31;
  int q4 = q * 4;

  for (int n = hw; n < 32; n += 8) {
    int v = nbase + n;
    float ax = 0.f, ay = 0.f, az = 0.f, aw = 0.f;
    float hx = 0.f, hy = 0.f, hz = 0.f, hwv = 0.f;
    if (v < NN) {
      int r0 = row_start[v];
      int dgv = deg[v];
      int i = 0;
      for (; i + 7 < dgv; i += 8) {
        int s[8];
#pragma unroll
        for (int u = 0; u < 8; ++u) s[u] = eid[r0 + i + u];
        ushort4 rowv[8];
#pragma unroll
        for (int u = 0; u < 8; ++u)
          rowv[u] = *reinterpret_cast<const ushort4*>(featb + (size_t)s[u] * CH + q4);
#pragma unroll
        for (int u = 0; u < 8; ++u) {
          ax += bf2f(rowv[u].x);
          ay += bf2f(rowv[u].y);
          az += bf2f(rowv[u].z);
          aw += bf2f(rowv[u].w);
        }
      }
      for (; i < dgv; ++i) {
        int s0 = eid[r0 + i];
        ushort4 a = *reinterpret_cast<const ushort4*>(featb + (size_t)s0 * CH + q4);
        ax += bf2f(a.x); ay += bf2f(a.y); az += bf2f(a.z); aw += bf2f(a.w);
      }
      float r = 1.0f / (float)max(dgv, 1);
      ax *= r; ay *= r; az *= r; aw *= r;
      if (feat32) {
        float4 hh = *reinterpret_cast<const float4*>(feat32 + (size_t)v * CH + q4);
        hx = hh.x; hy = hh.y; hz = hh.z; hwv = hh.w;
      } else {
        ushort4 hb = *reinterpret_cast<const ushort4*>(featb + (size_t)v * CH + q4);
        hx = bf2f(hb.x); hy = bf2f(hb.y); hz = bf2f(hb.z); hwv = bf2f(hb.w);
      }
    }
    *reinterpret_cast<float4*>(&mean_s[n][q4]) = make_float4(ax, ay, az, aw);
    *reinterpret_cast<float4*>(&h_s[n][q4]) = make_float4(hx, hy, hz, hwv);
  }
  __syncthreads();

  int jg = tid & 31, ng = tid >> 5;
  int j0 = jg * 4, nl = ng * 4;
  float acc[4][4];
#pragma unroll
  for (int a = 0; a < 4; a++)
#pragma unroll
    for (int b = 0; b < 4; b++) acc[a][b] = 0.f;

#pragma unroll 4
  for (int k = 0; k < 128; ++k) {
    float4 wl = *reinterpret_cast<const float4*>(Wl + k * CH + j0);
    float4 wr = *reinterpret_cast<const float4*>(Wr + k * CH + j0);
#pragma unroll
    for (int n = 0; n < 4; ++n) {
      float m = mean_s[nl + n][k];
      float hv = h_s[nl + n][k];
      acc[n][0] += m * wl.x + hv * wr.x;
      acc[n][1] += m * wl.y + hv * wr.y;
      acc[n][2] += m * wl.z + hv * wr.z;
      acc[n][3] += m * wl.w + hv * wr.w;
    }
  }

  float4 bb = *reinterpret_cast<const float4*>(bias + j0);
#pragma unroll
  for (int n = 0; n < 4; ++n) {
    int v = nbase + nl + n;
    if (v < NN) {
      float4 o;
      o.x = fmaxf(acc[n][0] + bb.x, 0.f);
      o.y = fmaxf(acc[n][1] + bb.y, 0.f);
      o.z = fmaxf(acc[n][2] + bb.z, 0.f);
      o.w = fmaxf(acc[n][3] + bb.w, 0.f);
      if (outf) *reinterpret_cast<float4*>(outf + (size_t)v * CH + j0) = o;
      if (outb) {
        ushort4 ob;
        ob.x = f2bf(o.x); ob.y = f2bf(o.y); ob.z = f2bf(o.z); ob.w = f2bf(o.w);
        *reinterpret_cast<ushort4*>(outb + (size_t)v * CH + j0) = ob;
      }
    }
  }
}

// ------- mu / logvar heads + reparameterize (fp32 h2 in, bf16 z out) -------
__global__ __launch_bounds__(256) void k_heads(
    const float* __restrict__ h2, const float* __restrict__ eps,
    const float* __restrict__ Wmu, const float* __restrict__ bmu,
    const float* __restrict__ Wlv, const float* __restrict__ blv,
    float* __restrict__ mu_out, float* __restrict__ lv_out,
    unsigned short* __restrict__ zb) {
  __shared__ float hs[32][132];  // +4 pad kills bank conflict on hs[n][k]
  int tid = threadIdx.x;
  int nbase = blockIdx.x * 32;

  for (int f = tid; f < 1024; f += 256) {
    int row = f >> 5;
    int c4 = (f & 31) * 4;
    int v = nbase + row;
    float4 hh = make_float4(0.f, 0.f, 0.f, 0.f);
    if (v < NN) hh = *reinterpret_cast<const float4*>(h2 + (size_t)v * CH + c4);
    *reinterpret_cast<float4*>(&hs[row][c4]) = hh;
  }
  __syncthreads();

  int n = tid >> 3;
  int j0 = (tid & 7) * 4;
  float am[4] = {0.f, 0.f, 0.f, 0.f};
  float al[4] = {0.f, 0.f, 0.f, 0.f};
#pragma unroll 4
  for (int k = 0; k < 128; ++k) {
    float4 wm = *reinterpret_cast<const float4*>(Wmu + k * LAT + j0);
    float4 wv = *reinterpret_cast<const float4*>(Wlv + k * LAT + j0);
    float hv = hs[n][k];
    am[0] += hv * wm.x; am[1] += hv * wm.y; am[2] += hv * wm.z; am[3] += hv * wm.w;
    al[0] += hv * wv.x; al[1] += hv * wv.y; al[2] += hv * wv.z; al[3] += hv * wv.w;
  }
  int v = nbase + n;
  if (v < NN) {
    float4 bm = *reinterpret_cast<const float4*>(bmu + j0);
    float4 bl = *reinterpret_cast<const float4*>(blv + j0);
    float4 e4 = *reinterpret_cast<const float4*>(eps + (size_t)v * LAT + j0);
    float4 mu, lv;
    mu.x = am[0] + bm.x; mu.y = am[1] + bm.y; mu.z = am[2] + bm.z; mu.w = am[3] + bm.w;
    lv.x = al[0] + bl.x; lv.y = al[1] + bl.y; lv.z = al[2] + bl.z; lv.w = al[3] + bl.w;
    ushort4 zz;
    zz.x = f2bf(mu.x + e4.x * expf(0.5f * lv.x));
    zz.y = f2bf(mu.y + e4.y * expf(0.5f * lv.y));
    zz.z = f2bf(mu.z + e4.z * expf(0.5f * lv.z));
    zz.w = f2bf(mu.w + e4.w * expf(0.5f * lv.w));
    *reinterpret_cast<float4*>(mu_out + (size_t)v * LAT + j0) = mu;
    *reinterpret_cast<float4*>(lv_out + (size_t)v * LAT + j0) = lv;
    *reinterpret_cast<ushort4*>(zb + (size_t)v * LAT + j0) = zz;
  }
}

// ------- edge decode: sigmoid(z[src] . z[dst]), bf16 z, 4 lanes/edge -------
__global__ void k_decode(const int* __restrict__ src, const int* __restrict__ dst,
                         const unsigned short* __restrict__ zb,
                         float* __restrict__ probs) {
  int t = blockIdx.x * 256 + threadIdx.x;
  int e = t >> 2, part = t & 3;
  if (e >= NE) return;
  int s = src[e], d = dst[e];
  uint4 ua = *reinterpret_cast<const uint4*>(zb + (size_t)s * LAT + part * 8);
  uint4 ub = *reinterpret_cast<const uint4*>(zb + (size_t)d * LAT + part * 8);
  float p = bflo(ua.x) * bflo(ub.x) + bfhi(ua.x) * bfhi(ub.x)
          + bflo(ua.y) * bflo(ub.y) + bfhi(ua.y) * bfhi(ub.y)
          + bflo(ua.z) * bflo(ub.z) + bfhi(ua.z) * bfhi(ub.z)
          + bflo(ua.w) * bflo(ub.w) + bfhi(ua.w) * bfhi(ub.w);
  p += __shfl_xor(p, 1);
  p += __shfl_xor(p, 2);
  if (part == 0) probs[e] = 1.0f / (1.0f + expf(-p));
}

extern "C" void kernel_launch(void* const* d_in, const int* in_sizes, int n_in,
                              void* d_out, int out_size, void* d_ws, size_t ws_size,
                              hipStream_t stream) {
  const float* x   = (const float*)d_in[0];
  const int*   ei  = (const int*)d_in[1];
  const float* eps = (const float*)d_in[2];
  const float* Wl0 = (const float*)d_in[3];
  const float* Wr0 = (const float*)d_in[4];
  const float* b0  = (const float*)d_in[5];
  const float* Wl1 = (const float*)d_in[6];
  const float* Wr1 = (const float*)d_in[7];
  const float* b1  = (const float*)d_in[8];
  const float* Wmu = (const float*)d_in[9];
  const float* bmu = (const float*)d_in[10];
  const float* Wlv = (const float*)d_in[11];
  const float* blv = (const float*)d_in[12];
  const int* src = ei;
  const int* dst = ei + NE;

  // workspace layout (R4-proven, ~55.5 MiB)
  int* iws = (int*)d_ws;
  int* deg       = iws;                       // NN
  int* row_start = deg + NN;                  // NN
  int* cursor    = row_start + NN;            // NN
  int* bsum      = cursor + NN;               // 256
  int* boff      = bsum + 256;                // 256
  int* eid       = boff + 256;                // NE
  unsigned short* xb  = (unsigned short*)(eid + NE);  // NN*CH bf16
  unsigned short* h1b = xb + (size_t)NN * CH;         // NN*CH bf16
  float* h2 = (float*)(h1b + (size_t)NN * CH);        // NN*CH fp32
  unsigned short* zb = xb;  // xb dead after layer 0; NN*LAT bf16 fits

  float* probs  = (float*)d_out;              // NE
  float* mu_out = probs + NE;                 // NN*LAT
  float* lv_out = mu_out + NN * LAT;          // NN*LAT

  hipMemsetAsync(deg, 0, NN * sizeof(int), stream);

  k_tobf16<<<(NN * CH / 4 + 255) / 256, 256, 0, stream>>>(x, xb, NN * CH / 4);
  k_hist <<<(NE + 255) / 256, 256, 0, stream>>>(dst, deg);
  k_scan1<<<NB, 256, 0, stream>>>(deg, bsum);
  k_scan2<<<1, 256, 0, stream>>>(bsum, boff);
  k_scan3<<<NB, 256, 0, stream>>>(deg, boff, row_start, cursor);
  k_fill <<<(NE + 255) / 256, 256, 0, stream>>>(src, dst, cursor, eid);

  // layer 0: gather bf16(x), self exact fp32 x, emit bf16 h1
  k_sage2<<<(NN + 31) / 32, 256, 0, stream>>>(xb, x, deg, row_start, eid,
                                              Wl0, Wr0, b0, nullptr, h1b);
  // layer 1: gather + self bf16 h1, emit fp32 h2
  k_sage2<<<(NN + 31) / 32, 256, 0, stream>>>(h1b, nullptr, deg, row_start, eid,
                                              Wl1, Wr1, b1, h2, nullptr);

  k_heads<<<(NN + 31) / 32, 256, 0, stream>>>(h2, eps, Wmu, bmu, Wlv, blv,
                                              mu_out, lv_out, zb);
  k_decode<<<(NE * 4 + 255) / 256, 256, 0, stream>>>(src, dst, zb, probs);
}